// Round 1
// baseline (137.734 us; speedup 1.0000x reference)
//
#include <hip/hip_runtime.h>
#include <cstdint>

#define D_MODEL 128
#define D_EMB   64
#define MAXLEN  32
#define NB      2
#define NMSA    4
#define LL      768

// P[b*L+i][d] = sum_k e[b,i,k] * W_proj[k][d]
// Q[b*L+i][d] = sum_k e[b,i,k] * W_proj[64+k][d]
__global__ void pq_kernel(const int* __restrict__ msa_tokens,
                          const float* __restrict__ emb,
                          const float* __restrict__ W_proj,
                          float* __restrict__ P, float* __restrict__ Q) {
    int bi = blockIdx.x;            // 0 .. NB*LL-1
    int b  = bi / LL;
    int i  = bi - b * LL;
    int d  = threadIdx.x;           // 0 .. 127
    __shared__ float e[D_EMB];
    int tok = msa_tokens[(b * NMSA + 0) * LL + i];
    if (d < D_EMB) {
        e[d] = (tok != 0) ? emb[tok * D_EMB + d] : 0.0f;
    }
    __syncthreads();
    float p = 0.f, q = 0.f;
    #pragma unroll
    for (int k = 0; k < D_EMB; ++k) {
        float ek = e[k];
        p = fmaf(ek, W_proj[k * D_MODEL + d], p);
        q = fmaf(ek, W_proj[(D_EMB + k) * D_MODEL + d], q);
    }
    P[bi * D_MODEL + d] = p;
    Q[bi * D_MODEL + d] = q;
}

// R[r][d] = W_pos[r][d] + b_pos[d] + b_proj[d],  r in [0, 63)
__global__ void r_kernel(const float* __restrict__ W_pos,
                         const float* __restrict__ b_pos,
                         const float* __restrict__ b_proj,
                         float* __restrict__ R) {
    int idx = blockIdx.x * blockDim.x + threadIdx.x;
    if (idx < (2 * MAXLEN - 1) * D_MODEL) {
        int d = idx & (D_MODEL - 1);
        R[idx] = W_pos[idx] + b_pos[d] + b_proj[d];
    }
}

// out[b,i,j,d] = P[b,i,d] + Q[b,j,d] + R[clip(i-j,-31,31)+31, d]
__global__ __launch_bounds__(256) void fill_kernel(
        const float* __restrict__ P, const float* __restrict__ Q,
        const float* __restrict__ R, float* __restrict__ out) {
    int bi    = blockIdx.x;         // b*LL + i
    int b     = bi / LL;
    int i     = bi - b * LL;
    int jbase = blockIdx.y * 64;
    int t     = threadIdx.x;
    int d4    = t & 31;             // which float4 of the 128-dim channel
    int jo    = t >> 5;             // 0..7

    float4 p = reinterpret_cast<const float4*>(P + (size_t)bi * D_MODEL)[d4];
    const float4* Qb = reinterpret_cast<const float4*>(Q + (size_t)b * LL * D_MODEL);
    const float4* R4 = reinterpret_cast<const float4*>(R);
    float4* orow = reinterpret_cast<float4*>(out + ((size_t)bi * LL + jbase) * D_MODEL);

    #pragma unroll
    for (int jj = 0; jj < 64; jj += 8) {
        int j = jbase + jj + jo;
        int rel = i - j;
        rel = rel > (MAXLEN - 1) ? (MAXLEN - 1) : rel;
        rel = rel < -(MAXLEN - 1) ? -(MAXLEN - 1) : rel;
        rel += MAXLEN - 1;

        float4 q = Qb[(size_t)j * 32 + d4];
        float4 r = R4[rel * 32 + d4];
        float4 o;
        o.x = p.x + q.x + r.x;
        o.y = p.y + q.y + r.y;
        o.z = p.z + q.z + r.z;
        o.w = p.w + q.w + r.w;
        orow[(size_t)(jj + jo) * 32 + d4] = o;
    }
}

extern "C" void kernel_launch(void* const* d_in, const int* in_sizes, int n_in,
                              void* d_out, int out_size, void* d_ws, size_t ws_size,
                              hipStream_t stream) {
    const int*   msa    = (const int*)d_in[0];
    const float* emb    = (const float*)d_in[1];
    const float* W_proj = (const float*)d_in[2];
    const float* b_proj = (const float*)d_in[3];
    const float* W_pos  = (const float*)d_in[4];
    const float* b_pos  = (const float*)d_in[5];
    float* out = (float*)d_out;

    float* P = (float*)d_ws;                       // NB*LL*128 floats
    float* Q = P + (size_t)NB * LL * D_MODEL;      // NB*LL*128 floats
    float* R = Q + (size_t)NB * LL * D_MODEL;      // 63*128 floats

    pq_kernel<<<NB * LL, D_MODEL, 0, stream>>>(msa, emb, W_proj, P, Q);
    r_kernel<<<((2 * MAXLEN - 1) * D_MODEL + 255) / 256, 256, 0, stream>>>(W_pos, b_pos, b_proj, R);
    fill_kernel<<<dim3(NB * LL, LL / 64), 256, 0, stream>>>(P, Q, R, out);
}

// Round 3
// 131.001 us; speedup vs baseline: 1.0514x; 1.0514x over previous
//
#include <hip/hip_runtime.h>
#include <cstdint>

#define D_MODEL 128
#define D_EMB   64
#define MAXLEN  32
#define NB      2
#define NMSA    4
#define LL      768
#define JCHUNK  128   // j's per block in fill kernel

typedef float f32x4 __attribute__((ext_vector_type(4)));

// P[b*L+i][d] = sum_k e[b,i,k] * W_proj[k][d]
// Q[b*L+i][d] = sum_k e[b,i,k] * W_proj[64+k][d]
__global__ void pq_kernel(const int* __restrict__ msa_tokens,
                          const float* __restrict__ emb,
                          const float* __restrict__ W_proj,
                          float* __restrict__ P, float* __restrict__ Q) {
    int bi = blockIdx.x;            // 0 .. NB*LL-1
    int b  = bi / LL;
    int i  = bi - b * LL;
    int d  = threadIdx.x;           // 0 .. 127
    __shared__ float e[D_EMB];
    int tok = msa_tokens[(b * NMSA + 0) * LL + i];
    if (d < D_EMB) {
        e[d] = (tok != 0) ? emb[tok * D_EMB + d] : 0.0f;
    }
    __syncthreads();
    float p = 0.f, q = 0.f;
    #pragma unroll
    for (int k = 0; k < D_EMB; ++k) {
        float ek = e[k];
        p = fmaf(ek, W_proj[k * D_MODEL + d], p);
        q = fmaf(ek, W_proj[(D_EMB + k) * D_MODEL + d], q);
    }
    P[bi * D_MODEL + d] = p;
    Q[bi * D_MODEL + d] = q;
}

// R[r][d] = W_pos[r][d] + b_pos[d] + b_proj[d],  r in [0, 63)
__global__ void r_kernel(const float* __restrict__ W_pos,
                         const float* __restrict__ b_pos,
                         const float* __restrict__ b_proj,
                         float* __restrict__ R) {
    int idx = blockIdx.x * blockDim.x + threadIdx.x;
    if (idx < (2 * MAXLEN - 1) * D_MODEL) {
        int d = idx & (D_MODEL - 1);
        R[idx] = W_pos[idx] + b_pos[d] + b_proj[d];
    }
}

// out[b,i,j,d] = P[b,i,d] + Q[b,j,d] + R[clip(i-j,-31,31)+31, d]
// Nontemporal stores: output is write-once, never re-read -> bypass L2 so
// the resident Q/R working set stays hot.
__global__ __launch_bounds__(256) void fill_kernel(
        const float* __restrict__ P, const float* __restrict__ Q,
        const float* __restrict__ R, float* __restrict__ out) {
    int bi    = blockIdx.x;         // b*LL + i
    int b     = bi / LL;
    int i     = bi - b * LL;
    int jbase = blockIdx.y * JCHUNK;
    int t     = threadIdx.x;
    int d4    = t & 31;             // which float4 of the 128-dim channel
    int jo    = t >> 5;             // 0..7

    const f32x4* P4 = reinterpret_cast<const f32x4*>(P);
    const f32x4* Qb = reinterpret_cast<const f32x4*>(Q + (size_t)b * LL * D_MODEL);
    const f32x4* R4 = reinterpret_cast<const f32x4*>(R);
    f32x4* orow = reinterpret_cast<f32x4*>(out + ((size_t)bi * LL + jbase) * D_MODEL);

    f32x4 p = P4[(size_t)bi * 32 + d4];

    #pragma unroll
    for (int jj = 0; jj < JCHUNK; jj += 8) {
        int j = jbase + jj + jo;
        int rel = i - j;
        rel = rel > (MAXLEN - 1) ? (MAXLEN - 1) : rel;
        rel = rel < -(MAXLEN - 1) ? -(MAXLEN - 1) : rel;
        rel += MAXLEN - 1;

        f32x4 q = Qb[(size_t)j * 32 + d4];
        f32x4 r = R4[rel * 32 + d4];
        f32x4 o = p + q + r;
        __builtin_nontemporal_store(o, &orow[(size_t)(jj + jo) * 32 + d4]);
    }
}

extern "C" void kernel_launch(void* const* d_in, const int* in_sizes, int n_in,
                              void* d_out, int out_size, void* d_ws, size_t ws_size,
                              hipStream_t stream) {
    const int*   msa    = (const int*)d_in[0];
    const float* emb    = (const float*)d_in[1];
    const float* W_proj = (const float*)d_in[2];
    const float* b_proj = (const float*)d_in[3];
    const float* W_pos  = (const float*)d_in[4];
    const float* b_pos  = (const float*)d_in[5];
    float* out = (float*)d_out;

    float* P = (float*)d_ws;                       // NB*LL*128 floats
    float* Q = P + (size_t)NB * LL * D_MODEL;      // NB*LL*128 floats
    float* R = Q + (size_t)NB * LL * D_MODEL;      // 63*128 floats

    pq_kernel<<<NB * LL, D_MODEL, 0, stream>>>(msa, emb, W_proj, P, Q);
    r_kernel<<<((2 * MAXLEN - 1) * D_MODEL + 255) / 256, 256, 0, stream>>>(W_pos, b_pos, b_proj, R);
    fill_kernel<<<dim3(NB * LL, LL / JCHUNK), 256, 0, stream>>>(P, Q, R, out);
}